// Round 3
// baseline (523.652 us; speedup 1.0000x reference)
//
#include <hip/hip_runtime.h>

// HybridSatelliteNormalizer: per-(B,C) channel percentile normalization.
// x: (16,3,1024,1024) fp32. 48 channels x 1,048,576 px each.
//
// Exact k-th-value selection via 2-level histogram (1024 coarse x 1024 fine
// = 2^20 virtual bins, value error <= 4.8e-7), then a streaming apply pass.
//
// R1/R2 changes vs R0 (dur 413.6 us):
//  - hist flush via per-block slabs (no global atomics, no memset dispatch)
//  - sub-hist zeroing folded into k_select_coarse (6 -> 5 dispatches)
//  - k_apply: __powf fast intrinsic (v_log_f32 + v_exp_f32)
//  - k_apply: nontemporal stores via clang ext_vector_type (HIP float4 is a
//    class type the builtin rejects -- R2 compile fix)
//  - params pre-folded to {min, 1/scale, 1/std, -mean/std} -> epilogue = 1 fma

#define HW (1024 * 1024)
#define NCH 48
#define BPC 32                        // blocks per channel
#define GRID_STREAM (NCH * BPC)       // 1536 blocks
#define EPB (HW / BPC)                // 32768 elements per block
#define F4PT (EPB / 4 / 256)          // 32 float4 per thread

typedef float vfloat4 __attribute__((ext_vector_type(4)));

// ---------------- Pass A: coarse histogram -> per-block slabs ---------------
__global__ __launch_bounds__(256) void k_hist(const float* __restrict__ x,
                                              unsigned* __restrict__ slab) {
    __shared__ unsigned lh[1024];
    const int t = threadIdx.x;
    for (int i = t; i < 1024; i += 256) lh[i] = 0u;
    __syncthreads();

    const float4* __restrict__ xv = (const float4*)x + (long long)blockIdx.x * (EPB / 4);

#pragma unroll 8
    for (int i = 0; i < F4PT; ++i) {
        float4 v = xv[i * 256 + t];
        float f[4] = {v.x, v.y, v.z, v.w};
#pragma unroll
        for (int k = 0; k < 4; ++k) {
            if (f[k] > 1e-4f) {
                int j = (int)(f[k] * 1048576.0f);
                j = min(j, 1048575);
                atomicAdd(&lh[j >> 10], 1u);
            }
        }
    }
    __syncthreads();
    unsigned* s = slab + (size_t)blockIdx.x * 1024;
    for (int i = t; i < 1024; i += 256) s[i] = lh[i];
}

// -------- Select coarse bin per channel; zero sub-hists for pass B ----------
__global__ __launch_bounds__(1024) void k_select_coarse(const unsigned* __restrict__ slab,
                                                        int* __restrict__ info,
                                                        unsigned* __restrict__ sub2,
                                                        unsigned* __restrict__ sub98) {
    __shared__ unsigned s[1024];
    __shared__ int sh[4];  // {b2, r2, b98, r98}
    const int c = blockIdx.x, t = threadIdx.x;

    unsigned sum = 0;
    const unsigned* base = slab + (size_t)c * BPC * 1024;
#pragma unroll
    for (int b = 0; b < BPC; ++b) sum += base[b * 1024 + t];
    s[t] = sum;

    sub2[c * 1024 + t] = 0u;   // zero pass-B sub-histograms
    sub98[c * 1024 + t] = 0u;
    if (t < 4) sh[t] = 0;
    __syncthreads();

    for (int off = 1; off < 1024; off <<= 1) {
        unsigned v = (t >= off) ? s[t - off] : 0u;
        __syncthreads();
        s[t] += v;
        __syncthreads();
    }
    const int n = (int)s[1023];
    if (n > 0) {
        // reference: k = min(p*n//100 + 1, n); idx = max(k-1,0) = min(p*n/100, n-1)
        const int i2 = min((2 * n) / 100, n - 1);
        const int i98 = min((98 * n) / 100, n - 1);  // 98*n < 2^31, fits int32
        const unsigned excl = (t == 0) ? 0u : s[t - 1];
        const unsigned incl = s[t];
        if (excl <= (unsigned)i2 && (unsigned)i2 < incl) { sh[0] = t; sh[1] = i2 - (int)excl; }
        if (excl <= (unsigned)i98 && (unsigned)i98 < incl) { sh[2] = t; sh[3] = i98 - (int)excl; }
    }
    __syncthreads();
    if (t == 0) {
        info[c * 8 + 0] = n;
        info[c * 8 + 1] = sh[0];
        info[c * 8 + 2] = sh[1];
        info[c * 8 + 3] = sh[2];
        info[c * 8 + 4] = sh[3];
    }
}

// ---------------- Pass B: fine sub-histograms of the 2 candidate bins -------
__global__ __launch_bounds__(256) void k_refine(const float* __restrict__ x,
                                                const int* __restrict__ info,
                                                unsigned* __restrict__ sub2,
                                                unsigned* __restrict__ sub98) {
    const int ch = blockIdx.x / BPC;
    const int b2 = info[ch * 8 + 1];
    const int b98 = info[ch * 8 + 3];
    const float4* __restrict__ xv = (const float4*)x + (long long)blockIdx.x * (EPB / 4);
    const int t = threadIdx.x;

#pragma unroll 8
    for (int i = 0; i < F4PT; ++i) {
        float4 v = xv[i * 256 + t];
        float f[4] = {v.x, v.y, v.z, v.w};
#pragma unroll
        for (int k = 0; k < 4; ++k) {
            if (f[k] > 1e-4f) {
                int j = (int)(f[k] * 1048576.0f);  // identical expr to pass A
                j = min(j, 1048575);
                const int cb = j >> 10, fb = j & 1023;
                if (cb == b2) atomicAdd(&sub2[ch * 1024 + fb], 1u);
                if (cb == b98) atomicAdd(&sub98[ch * 1024 + fb], 1u);
            }
        }
    }
}

// ---------------- Select fine bin -> per-channel params ---------------------
__global__ __launch_bounds__(1024) void k_select_fine(const unsigned* __restrict__ sub2,
                                                      const unsigned* __restrict__ sub98,
                                                      const int* __restrict__ info,
                                                      float* __restrict__ params) {
    __shared__ unsigned s[1024];
    __shared__ int fb2s, fb98s;
    const int c = blockIdx.x, t = threadIdx.x;
    const int n = info[c * 8 + 0];
    const int b2 = info[c * 8 + 1], r2 = info[c * 8 + 2];
    const int b98 = info[c * 8 + 3], r98 = info[c * 8 + 4];
    if (t == 0) { fb2s = 0; fb98s = 0; }

    s[t] = sub2[c * 1024 + t];
    __syncthreads();
    for (int off = 1; off < 1024; off <<= 1) {
        unsigned v = (t >= off) ? s[t - off] : 0u;
        __syncthreads();
        s[t] += v;
        __syncthreads();
    }
    {
        const unsigned excl = (t == 0) ? 0u : s[t - 1];
        if (excl <= (unsigned)r2 && (unsigned)r2 < s[t]) fb2s = t;
    }
    __syncthreads();

    s[t] = sub98[c * 1024 + t];
    __syncthreads();
    for (int off = 1; off < 1024; off <<= 1) {
        unsigned v = (t >= off) ? s[t - off] : 0u;
        __syncthreads();
        s[t] += v;
        __syncthreads();
    }
    {
        const unsigned excl = (t == 0) ? 0u : s[t - 1];
        if (excl <= (unsigned)r98 && (unsigned)r98 < s[t]) fb98s = t;
    }
    __syncthreads();

    if (t == 0) {
        const bool use = n > 100;
        const float v2 = ((float)(b2 * 1024 + fb2s) + 0.5f) * (1.0f / 1048576.0f);
        const float v98 = ((float)(b98 * 1024 + fb98s) + 0.5f) * (1.0f / 1048576.0f);
        const float mn = use ? v2 : 0.0f;
        const float mx = use ? v98 : 1.0f;
        const float sc = fmaxf(mx - mn, 1e-6f);
        const float mean3[3] = {0.485f, 0.456f, 0.406f};
        const float std3[3] = {0.229f, 0.224f, 0.225f};
        const int c3 = c % 3;
        const float istd = 1.0f / std3[c3];
        float4 p;
        p.x = mn;
        p.y = 1.0f / sc;
        p.z = istd;                    // multiply
        p.w = -mean3[c3] * istd;       // fused add -> epilogue is one fma
        ((float4*)params)[c] = p;
    }
}

// ---------------- Pass C: apply -------------------------------------------
__device__ __forceinline__ float apply_one(float xx, float4 p) {
    float y = (xx - p.x) * p.y;
    y = fminf(fmaxf(y, 0.0f), 1.0f);
    // y^(1/2.2): __powf lowers to v_log_f32 + v_mul + v_exp_f32 (fast path);
    // guard keeps exact 0 at y==0 like the reference
    float pw = (y > 0.0f) ? __powf(y, 0.45454547f) : 0.0f;
    return fmaf(pw, p.z, p.w);
}

__global__ __launch_bounds__(256) void k_apply(const float* __restrict__ x,
                                               float* __restrict__ out,
                                               const float4* __restrict__ params) {
    const int ch = blockIdx.x / BPC;
    const float4 p = params[ch];
    const long long base_f4 = (long long)blockIdx.x * (EPB / 4);
    const float4* __restrict__ xv = (const float4*)x + base_f4;
    vfloat4* __restrict__ ov = (vfloat4*)out + base_f4;
    const int t = threadIdx.x;

#pragma unroll 8
    for (int i = 0; i < F4PT; ++i) {
        float4 v = xv[i * 256 + t];
        vfloat4 r;
        r.x = apply_one(v.x, p);
        r.y = apply_one(v.y, p);
        r.z = apply_one(v.z, p);
        r.w = apply_one(v.w, p);
        __builtin_nontemporal_store(r, &ov[i * 256 + t]);
    }
}

extern "C" void kernel_launch(void* const* d_in, const int* in_sizes, int n_in,
                              void* d_out, int out_size, void* d_ws, size_t ws_size,
                              hipStream_t stream) {
    const float* x = (const float*)d_in[0];
    float* out = (float*)d_out;

    // workspace layout (4B units):
    //   slab  : 1536*1024 u32 (per-block coarse hists, fully overwritten)
    //   sub2  : 48*1024 u32   (zeroed by k_select_coarse)
    //   sub98 : 48*1024 u32   (zeroed by k_select_coarse)
    //   info  : 48*8 int      {n, b2, r2, b98, r98, -, -, -}
    //   params: 48*4 float    {min, 1/scale, 1/std, -mean/std}
    unsigned* slab = (unsigned*)d_ws;
    unsigned* sub2 = slab + (size_t)GRID_STREAM * 1024;
    unsigned* sub98 = sub2 + NCH * 1024;
    int* info = (int*)(sub98 + NCH * 1024);
    float* params = (float*)(info + NCH * 8);

    k_hist<<<GRID_STREAM, 256, 0, stream>>>(x, slab);
    k_select_coarse<<<NCH, 1024, 0, stream>>>(slab, info, sub2, sub98);
    k_refine<<<GRID_STREAM, 256, 0, stream>>>(x, info, sub2, sub98);
    k_select_fine<<<NCH, 1024, 0, stream>>>(sub2, sub98, info, params);
    k_apply<<<GRID_STREAM, 256, 0, stream>>>(x, out, (const float4*)params);
}